// Round 10
// baseline (341.552 us; speedup 1.0000x reference)
//
#include <hip/hip_runtime.h>

#define NHW 9216   // 96*96
#define NB 2
#define NCHUNK 16  // col chunks for k_simtop

typedef short s8v __attribute__((ext_vector_type(8)));       // 8x16-bit in 4 VGPRs
typedef _Float16 h8v __attribute__((ext_vector_type(8)));    // 8 f16
typedef float f4v __attribute__((ext_vector_type(4)));
typedef unsigned int u32;
typedef unsigned short u16;

__device__ inline u16 f2bf(float x) {
    u32 u = __float_as_uint(x);
    u += 0x7fffu + ((u >> 16) & 1u);          // round-to-nearest-even
    return (u16)(u >> 16);
}
__device__ inline u16 f2h(float x) {
    _Float16 h = (_Float16)x;
    return *(u16*)&h;
}

// ---------------------------------------------------------------------------
// K0a: transpose X [b][384][9216] fp32 -> xh f16 [g][384]. 3 passes/block.
// ---------------------------------------------------------------------------
__global__ __launch_bounds__(256) void k_xsplit(const float* __restrict__ X,
                                                u16* __restrict__ xh)
{
    __shared__ float fs[64][65];
    const int tid = threadIdx.x;
    const int b = blockIdx.z, p0 = blockIdx.x * 64, half = blockIdx.y;
    const size_t fb = (size_t)b * 384 * NHW;
    const int px = tid >> 2, sub = tid & 3;
    const size_t g = (size_t)b * NHW + p0 + px;
    for (int pass = half * 3; pass < half * 3 + 3; ++pass) {
        int c0p = pass * 64;
        __syncthreads();
#pragma unroll
        for (int r = 0; r < 16; ++r) {
            int e = r * 256 + tid;
            int cc = e >> 6, p = e & 63;
            fs[cc][p] = X[fb + (size_t)(c0p + cc) * NHW + p0 + p];
        }
        __syncthreads();
        u16 hb[16];
#pragma unroll
        for (int i = 0; i < 16; ++i) hb[i] = f2h(fs[sub * 16 + i][px]);
        size_t o = g * 384 + c0p + sub * 16;
        *(s8v*)&xh[o]     = *(s8v*)&hb[0];
        *(s8v*)&xh[o + 8] = *(s8v*)&hb[8];
    }
}

// ---------------------------------------------------------------------------
// K0b: W1 (98304) + W2 (32768) fp32 -> f16 hi/lo
// ---------------------------------------------------------------------------
__global__ __launch_bounds__(256) void k_wsplit(const float* __restrict__ W1,
                                                const float* __restrict__ W2,
                                                u16* __restrict__ w1h, u16* __restrict__ w1l,
                                                u16* __restrict__ w2h, u16* __restrict__ w2l)
{
    int i = blockIdx.x * 256 + threadIdx.x;
    if (i < 98304) {
        float v = W1[i];
        _Float16 h = (_Float16)v;
        w1h[i] = *(u16*)&h;
        w1l[i] = f2h(v - (float)h);
    } else {
        int j = i - 98304;
        float v = W2[j];
        _Float16 h = (_Float16)v;
        w2h[j] = *(u16*)&h;
        w2l[j] = f2h(v - (float)h);
    }
}

// ---------------------------------------------------------------------------
// K1: conv1 hh[g][256] = relu(xh @ (w1h+w1l)^T + b1), 2-term f16 MFMA.
// 128 px x 64 cout per block (grid 576 = 2.25/CU); B via global_load_lds
// double-buffer 2x16KB; A = direct s8v loads. XCD swizzle for A-tile L2 reuse.
// ---------------------------------------------------------------------------
__global__ __launch_bounds__(256, 4) void k_gemm1(const u16* __restrict__ xh,
                                                  const u16* __restrict__ w1h, const u16* __restrict__ w1l,
                                                  const float* __restrict__ b1,
                                                  u16* __restrict__ hh)
{
    union __align__(16) SM {
        struct { u16 B[2][16][512]; } stg;   // 32 KB staging
        u16 bounce[128 * 66];                // 16.9 KB epilogue transpose
    };
    __shared__ SM sm;
    const int tid = threadIdx.x;
    const int wave = tid >> 6, l = tid & 63, l15 = l & 15, q = l >> 4;
    // swizzle: 576 = 8 xcd x 72; px-group = xcd*18 + k/4, cout-block = k%4
    const int bx = blockIdx.x;
    const int xcd = bx & 7, k = bx >> 3;
    const int g0 = (xcd * 18 + (k >> 2)) * 128;
    const int c0 = (k & 3) * 64;
    const int gw = g0 + wave * 32;

    auto stage = [&](int kt, int buf) {
#pragma unroll
        for (int r = 0; r < 4; ++r) {
            int cid = r * 4 + wave;                 // cid = spl*8 + kf*4 + cs
            int spl = cid >> 3, kf = (cid >> 2) & 1, cs = cid & 3;
            const u16* src = (spl ? w1l : w1h) + (size_t)(c0 + cs * 16 + l15) * 384 + kt + kf * 32 + q * 8;
            __builtin_amdgcn_global_load_lds(
                (const __attribute__((address_space(1))) void*)src,
                (__attribute__((address_space(3))) void*)&sm.stg.B[buf][cid][0],
                16, 0, 0);
        }
    };

    f4v acc[2][4];
#pragma unroll
    for (int s = 0; s < 2; ++s)
#pragma unroll
        for (int c = 0; c < 4; ++c) acc[s][c] = (f4v){0.f, 0.f, 0.f, 0.f};

    stage(0, 0);
    __syncthreads();
    for (int t = 0; t < 6; ++t) {
        const int kt = t * 64;
        const int buf = t & 1;
        if (t < 5) stage(kt + 64, buf ^ 1);
        s8v ah[2][2];
#pragma unroll
        for (int s = 0; s < 2; ++s)
#pragma unroll
            for (int kf = 0; kf < 2; ++kf)
                ah[s][kf] = *(const s8v*)&xh[(size_t)(gw + s * 16 + l15) * 384 + kt + kf * 32 + q * 8];
#pragma unroll
        for (int kf = 0; kf < 2; ++kf)
#pragma unroll
            for (int cs = 0; cs < 4; ++cs) {
                s8v bh = *(const s8v*)&sm.stg.B[buf][kf * 4 + cs][l * 8];
                s8v bl = *(const s8v*)&sm.stg.B[buf][8 + kf * 4 + cs][l * 8];
#pragma unroll
                for (int s = 0; s < 2; ++s) {
                    acc[s][cs] = __builtin_amdgcn_mfma_f32_16x16x32_f16(*(h8v*)&ah[s][kf], *(h8v*)&bh, acc[s][cs], 0, 0, 0);
                    acc[s][cs] = __builtin_amdgcn_mfma_f32_16x16x32_f16(*(h8v*)&ah[s][kf], *(h8v*)&bl, acc[s][cs], 0, 0, 0);
                }
            }
        __syncthreads();
    }

    // epilogue: bias+relu, f16, LDS bounce transpose, coalesced [g][256] store
#pragma unroll
    for (int s = 0; s < 2; ++s)
#pragma unroll
        for (int cs = 0; cs < 4; ++cs) {
            int c = cs * 16 + l15;
            float bv = b1[c0 + c];
#pragma unroll
            for (int r = 0; r < 4; ++r) {
                int px = wave * 32 + s * 16 + q * 4 + r;   // C layout: row=q*4+r, col=l15
                sm.bounce[px * 66 + c] = f2h(fmaxf(acc[s][cs][r] + bv, 0.f));
            }
        }
    __syncthreads();
    {
        int px = tid >> 1, half = tid & 1;
        u32 tmp[16];
#pragma unroll
        for (int j = 0; j < 16; ++j)
            tmp[j] = *(const u32*)&sm.bounce[px * 66 + half * 32 + j * 2];
        size_t o = (size_t)(g0 + px) * 256 + c0 + half * 32;
#pragma unroll
        for (int j = 0; j < 4; ++j)
            *(s8v*)&hh[o + j * 8] = ((s8v*)tmp)[j];
    }
}

// ---------------------------------------------------------------------------
// K2: conv2 feat[g][128] = hh @ (w2h+w2l)^T + b2, 2-term f16 MFMA, fp32 out.
// 128 px x 32 cout per block (grid 576); whole W2 slice staged once (32 KB).
// ---------------------------------------------------------------------------
__global__ __launch_bounds__(256, 4) void k_gemm2(const u16* __restrict__ hh,
                                                  const u16* __restrict__ w2h, const u16* __restrict__ w2l,
                                                  const float* __restrict__ b2,
                                                  float* __restrict__ feat)
{
    __shared__ u16 Bs[32][512];   // 32 KB: cid = spl*16 + kf*2 + cs
    const int tid = threadIdx.x;
    const int wave = tid >> 6, l = tid & 63, l15 = l & 15, q = l >> 4;
    const int bx = blockIdx.x;
    const int xcd = bx & 7, k = bx >> 3;
    const int g0 = (xcd * 18 + (k >> 2)) * 128;
    const int c0 = (k & 3) * 32;

#pragma unroll
    for (int r = 0; r < 8; ++r) {
        int cid = r * 4 + wave;
        int spl = cid >> 4, kf = (cid >> 1) & 7, cs = cid & 1;
        const u16* src = (spl ? w2l : w2h) + (size_t)(c0 + cs * 16 + l15) * 256 + kf * 32 + q * 8;
        __builtin_amdgcn_global_load_lds(
            (const __attribute__((address_space(1))) void*)src,
            (__attribute__((address_space(3))) void*)&Bs[cid][0],
            16, 0, 0);
    }
    __syncthreads();

    const int gw = g0 + wave * 32;
    f4v acc[2][2];
#pragma unroll
    for (int s = 0; s < 2; ++s)
#pragma unroll
        for (int c = 0; c < 2; ++c) acc[s][c] = (f4v){0.f, 0.f, 0.f, 0.f};

#pragma unroll
    for (int kf = 0; kf < 8; ++kf) {
        s8v ah[2];
#pragma unroll
        for (int s = 0; s < 2; ++s)
            ah[s] = *(const s8v*)&hh[(size_t)(gw + s * 16 + l15) * 256 + kf * 32 + q * 8];
#pragma unroll
        for (int cs = 0; cs < 2; ++cs) {
            s8v bh = *(const s8v*)&Bs[kf * 2 + cs][l * 8];
            s8v bl = *(const s8v*)&Bs[16 + kf * 2 + cs][l * 8];
#pragma unroll
            for (int s = 0; s < 2; ++s) {
                acc[s][cs] = __builtin_amdgcn_mfma_f32_16x16x32_f16(*(h8v*)&ah[s], *(h8v*)&bh, acc[s][cs], 0, 0, 0);
                acc[s][cs] = __builtin_amdgcn_mfma_f32_16x16x32_f16(*(h8v*)&ah[s], *(h8v*)&bl, acc[s][cs], 0, 0, 0);
            }
        }
    }
#pragma unroll
    for (int s = 0; s < 2; ++s)
#pragma unroll
        for (int cs = 0; cs < 2; ++cs) {
            float bv = b2[c0 + cs * 16 + l15];
#pragma unroll
            for (int r = 0; r < 4; ++r)
                feat[(size_t)(gw + s * 16 + q * 4 + r) * 128 + c0 + cs * 16 + l15] = acc[s][cs][r] + bv;
        }
}

// ---------------------------------------------------------------------------
// K3: normalize rows of feat [g][128] -> rf fp32 + bf16 hi. 32 px/block.
// ---------------------------------------------------------------------------
__global__ __launch_bounds__(256) void k_norm2(const float* __restrict__ feat,
                                               float* __restrict__ rf,
                                               u16* __restrict__ hib)
{
    const int tid = threadIdx.x;
    const int px = blockIdx.x * 32 + (tid >> 3), part = tid & 7;
    const size_t o = (size_t)px * 128 + part * 16;
    f4v v[4];
    float ss = 0.f;
#pragma unroll
    for (int j = 0; j < 4; ++j) {
        v[j] = *(const f4v*)&feat[o + j * 4];
        ss += v[j][0]*v[j][0] + v[j][1]*v[j][1] + v[j][2]*v[j][2] + v[j][3]*v[j][3];
    }
    ss += __shfl_xor(ss, 1, 64);
    ss += __shfl_xor(ss, 2, 64);
    ss += __shfl_xor(ss, 4, 64);
    const float mx = fmaxf(sqrtf(ss), 1e-12f);
    u16 hb[16];
#pragma unroll
    for (int j = 0; j < 4; ++j) {
        f4v w;
#pragma unroll
        for (int e = 0; e < 4; ++e) {
            float val = v[j][e] / mx;
            w[e] = val;
            hb[j * 4 + e] = f2bf(val);
        }
        *(f4v*)&rf[o + j * 4] = w;
    }
    *(s8v*)&hib[o]     = *(s8v*)&hb[0];
    *(s8v*)&hib[o + 8] = *(s8v*)&hb[8];
}

// ---------------------------------------------------------------------------
// K4: sim selection via 1-term bf16 MFMA + sortable-key argmax (R8-proven).
// R10: __launch_bounds__(256,4) -> 4 blocks/CU (VGPR 108 fits 128 cap).
// ---------------------------------------------------------------------------
__global__ __launch_bounds__(256, 4) void k_simtop(const u16* __restrict__ hi,
                                                   int* __restrict__ cidx)
{
    __shared__ u16 Bs[2][16][512];
    const int tid  = threadIdx.x;
    const int wave = tid >> 6, l = tid & 63, l15 = l & 15, q = l >> 4;
    const int b     = blockIdx.z;
    const int rbase = blockIdx.x * 256;
    const int chunk = blockIdx.y;
    const int cbase = chunk * 576;
    const size_t base = (size_t)b * NHW;
    const int wr0 = rbase + wave * 64;

    s8v ah[4][4];
#pragma unroll
    for (int s = 0; s < 4; ++s) {
        int row = wr0 + s * 16 + l15;
#pragma unroll
        for (int kf = 0; kf < 4; ++kf)
            ah[s][kf] = *(const s8v*)&hi[(base + row) * 128 + kf * 32 + q * 8];
    }

    auto stage = [&](int colt, int buf) {
#pragma unroll
        for (int r = 0; r < 4; ++r) {
            int cid = r * 4 + wave;
            int kf = cid >> 2, cs = cid & 3;
            int col = colt + cs * 16 + l15;
            const u16* src = hi + (base + col) * 128 + kf * 32 + q * 8;
            __builtin_amdgcn_global_load_lds(
                (const __attribute__((address_space(1))) void*)src,
                (__attribute__((address_space(3))) void*)&Bs[buf][cid][0],
                16, 0, 0);
        }
    };

    u32 bk[4][4];
#pragma unroll
    for (int s = 0; s < 4; ++s)
#pragma unroll
        for (int r = 0; r < 4; ++r) bk[s][r] = 0u;

    stage(cbase, 0);
    __syncthreads();

    for (int ct = 0; ct < 9; ++ct) {
        const int colt = cbase + ct * 64;
        const int buf  = ct & 1;
        if (ct < 8) stage(colt + 64, buf ^ 1);

        f4v acc[4][4];
#pragma unroll
        for (int s = 0; s < 4; ++s)
#pragma unroll
            for (int c = 0; c < 4; ++c) acc[s][c] = (f4v){2.f, 2.f, 2.f, 2.f};

#pragma unroll
        for (int kf = 0; kf < 4; ++kf)
#pragma unroll
            for (int cs = 0; cs < 4; ++cs) {
                s8v bh = *(const s8v*)&Bs[buf][kf * 4 + cs][l * 8];
#pragma unroll
                for (int s = 0; s < 4; ++s)
                    acc[s][cs] = __builtin_amdgcn_mfma_f32_16x16x32_bf16(ah[s][kf], bh, acc[s][cs], 0, 0, 0);
            }

        const u32 tagv = (u32)(ct << 2);
        const bool hasdiag = (colt < wr0 + 64) && (wr0 < colt + 64);
        if (hasdiag) {
#pragma unroll
            for (int s = 0; s < 4; ++s)
#pragma unroll
                for (int r = 0; r < 4; ++r) {
                    const int rr = wr0 + s * 16 + q * 4 + r;
                    u32 km = 0u;
#pragma unroll
                    for (int cs = 0; cs < 4; ++cs) {
                        u32 kk = (__float_as_uint(acc[s][cs][r]) & 0xffffffc0u) | (tagv | (u32)cs);
                        if (colt + cs * 16 + l15 == rr) kk = 0u;
                        km = kk > km ? kk : km;
                    }
                    bk[s][r] = km > bk[s][r] ? km : bk[s][r];
                }
        } else {
#pragma unroll
            for (int s = 0; s < 4; ++s)
#pragma unroll
                for (int r = 0; r < 4; ++r) {
                    u32 km = 0u;
#pragma unroll
                    for (int cs = 0; cs < 4; ++cs) {
                        u32 kk = (__float_as_uint(acc[s][cs][r]) & 0xffffffc0u) | (tagv | (u32)cs);
                        km = kk > km ? kk : km;
                    }
                    bk[s][r] = km > bk[s][r] ? km : bk[s][r];
                }
        }
        __syncthreads();
    }

#pragma unroll
    for (int s = 0; s < 4; ++s)
#pragma unroll
        for (int r = 0; r < 4; ++r) {
            u32 key = bk[s][r];
            float v = __uint_as_float(key & 0xffffffc0u);
            int ctw = (int)((key >> 2) & 15u);
            int csw = (int)(key & 3u);
            int col = cbase + ctw * 64 + csw * 16 + l15;
#pragma unroll
            for (int d = 1; d < 16; d <<= 1) {
                float ov = __shfl_xor(v, d, 64);
                int   oi = __shfl_xor(col, d, 64);
                bool p = (ov > v) || (ov == v && oi < col);
                v   = p ? ov : v;
                col = p ? oi : col;
            }
            if (l15 == 0) {
                int row = wr0 + s * 16 + q * 4 + r;
                cidx[(base + row) * NCHUNK + chunk] = col;
            }
        }
}

// ---------------------------------------------------------------------------
// K5: exact fp32 re-rank of 16 candidates + distance + mask (R8-proven)
// ---------------------------------------------------------------------------
__global__ __launch_bounds__(256) void k_finish(const float* __restrict__ rf,
                                                const int* __restrict__ cidx,
                                                float* __restrict__ out)
{
    const int tid = threadIdx.x;
    const int g = blockIdx.x * 16 + (tid >> 4);
    const int l15 = tid & 15;
    const int b = g / NHW;
    const size_t rowbase = (size_t)b * NHW;

    const float* x = rf + (size_t)g * 128;
    f4v x0 = *(const f4v*)&x[l15 * 8];
    f4v x1 = *(const f4v*)&x[l15 * 8 + 4];

    float bestS = -2.f; int bestI = 0;
#pragma unroll
    for (int j = 0; j < NCHUNK; ++j) {
        int c = cidx[(size_t)g * NCHUNK + j];
        const float* y = rf + (rowbase + c) * 128;
        f4v y0 = *(const f4v*)&y[l15 * 8];
        f4v y1 = *(const f4v*)&y[l15 * 8 + 4];
        float s = x0[0]*y0[0] + x0[1]*y0[1] + x0[2]*y0[2] + x0[3]*y0[3]
                + x1[0]*y1[0] + x1[1]*y1[1] + x1[2]*y1[2] + x1[3]*y1[3];
#pragma unroll
        for (int d = 1; d < 16; d <<= 1) s += __shfl_xor(s, d, 64);
        bool p = (s > bestS) || (s == bestS && c < bestI);
        bestS = p ? s : bestS;
        bestI = p ? c : bestI;
    }

    const float* y = rf + (rowbase + bestI) * 128;
    f4v y0 = *(const f4v*)&y[l15 * 8];
    f4v y1 = *(const f4v*)&y[l15 * 8 + 4];
    float d0 = x0[0]-y0[0], d1 = x0[1]-y0[1], d2 = x0[2]-y0[2], d3 = x0[3]-y0[3];
    float e0 = x1[0]-y1[0], e1 = x1[1]-y1[1], e2 = x1[2]-y1[2], e3 = x1[3]-y1[3];
    float ss = d0*d0 + d1*d1 + d2*d2 + d3*d3 + e0*e0 + e1*e1 + e2*e2 + e3*e3;
#pragma unroll
    for (int d = 1; d < 16; d <<= 1) ss += __shfl_xor(ss, d, 64);
    if (l15 == 0) {
        float dist = sqrtf(ss);
        out[NB * NHW + g] = dist;
        out[g] = dist > 0.2f ? 1.0f : 0.0f;
    }
}

// ===========================================================================
extern "C" void kernel_launch(void* const* d_in, const int* in_sizes, int n_in,
                              void* d_out, int out_size, void* d_ws, size_t ws_size,
                              hipStream_t stream) {
    const float* features = (const float*)d_in[0];
    const float* W1 = (const float*)d_in[1];
    const float* b1 = (const float*)d_in[2];
    const float* W2 = (const float*)d_in[3];
    const float* b2 = (const float*)d_in[4];
    float* out = (float*)d_out;
    float* ws  = (float*)d_ws;

    // ws layout (float offsets), peak 6,029,312 f = 24.1 MB:
    //   [0,       3538944)  xh (18432x384 f16)  -> after gemm1: feat + hib
    //   [3538944, 5898240)  hh (18432x256 f16)  -> after gemm2: rf
    //   [5898240, 6029312)  w1h/w1l/w2h/w2l
    //   cidx aliases feat [0, 294912) after norm2.
    u16*   xh   = (u16*)ws;
    u16*   hh   = (u16*)(ws + 3538944);
    u16*   w1h  = (u16*)(ws + 5898240);
    u16*   w1l  = (u16*)(ws + 5947392);
    u16*   w2h  = (u16*)(ws + 5996544);
    u16*   w2l  = (u16*)(ws + 6012928);
    float* feat = ws;
    u16*   hib  = (u16*)(ws + 2359296);
    float* rf   = ws + 3538944;
    int*   cidx = (int*)ws;

    // transpose + f16 split of X (3 passes/block); weight splits
    k_xsplit<<<dim3(144, 2, NB), 256, 0, stream>>>(features, xh);
    k_wsplit<<<512, 256, 0, stream>>>(W1, W2, w1h, w1l, w2h, w2l);
    // conv1 (2-term f16 MFMA, 128px x 64cout, XCD-swizzled)
    k_gemm1<<<576, 256, 0, stream>>>(xh, w1h, w1l, b1, hh);
    // conv2 (2-term f16 MFMA, 128px x 32cout, XCD-swizzled)
    k_gemm2<<<576, 256, 0, stream>>>(hh, w2h, w2l, b2, feat);
    // L2 normalize + bf16 hi (32 px/block)
    k_norm2<<<576, 256, 0, stream>>>(feat, rf, hib);
    // 1-term bf16 sim selection: per-chunk argmax candidates
    k_simtop<<<dim3(36, NCHUNK, NB), 256, 0, stream>>>(hib, cidx);
    // exact fp32 re-rank of 16 candidates + distance + mask
    k_finish<<<1152, 256, 0, stream>>>(rf, cidx, out);
}

// Round 11
// 202.543 us; speedup vs baseline: 1.6863x; 1.6863x over previous
//
#include <hip/hip_runtime.h>

#define NHW 9216   // 96*96
#define NB 2
#define NCHUNK 16  // col chunks for k_simtop

typedef short s8v __attribute__((ext_vector_type(8)));       // 8x16-bit in 4 VGPRs
typedef _Float16 h8v __attribute__((ext_vector_type(8)));    // 8 f16
typedef float f4v __attribute__((ext_vector_type(4)));
typedef unsigned int u32;
typedef unsigned short u16;

__device__ inline u16 f2bf(float x) {
    u32 u = __float_as_uint(x);
    u += 0x7fffu + ((u >> 16) & 1u);          // round-to-nearest-even
    return (u16)(u >> 16);
}
__device__ inline u16 f2h(float x) {
    _Float16 h = (_Float16)x;
    return *(u16*)&h;
}

// ---------------------------------------------------------------------------
// K0a: transpose X [b][384][9216] fp32 -> xh f16 [g][384]. 3 passes/block.
// ---------------------------------------------------------------------------
__global__ __launch_bounds__(256) void k_xsplit(const float* __restrict__ X,
                                                u16* __restrict__ xh)
{
    __shared__ float fs[64][65];
    const int tid = threadIdx.x;
    const int b = blockIdx.z, p0 = blockIdx.x * 64, half = blockIdx.y;
    const size_t fb = (size_t)b * 384 * NHW;
    const int px = tid >> 2, sub = tid & 3;
    const size_t g = (size_t)b * NHW + p0 + px;
    for (int pass = half * 3; pass < half * 3 + 3; ++pass) {
        int c0p = pass * 64;
        __syncthreads();
#pragma unroll
        for (int r = 0; r < 16; ++r) {
            int e = r * 256 + tid;
            int cc = e >> 6, p = e & 63;
            fs[cc][p] = X[fb + (size_t)(c0p + cc) * NHW + p0 + p];
        }
        __syncthreads();
        u16 hb[16];
#pragma unroll
        for (int i = 0; i < 16; ++i) hb[i] = f2h(fs[sub * 16 + i][px]);
        size_t o = g * 384 + c0p + sub * 16;
        *(s8v*)&xh[o]     = *(s8v*)&hb[0];
        *(s8v*)&xh[o + 8] = *(s8v*)&hb[8];
    }
}

// ---------------------------------------------------------------------------
// K0b: W1 (98304) + W2 (32768) fp32 -> f16 hi/lo
// ---------------------------------------------------------------------------
__global__ __launch_bounds__(256) void k_wsplit(const float* __restrict__ W1,
                                                const float* __restrict__ W2,
                                                u16* __restrict__ w1h, u16* __restrict__ w1l,
                                                u16* __restrict__ w2h, u16* __restrict__ w2l)
{
    int i = blockIdx.x * 256 + threadIdx.x;
    if (i < 98304) {
        float v = W1[i];
        _Float16 h = (_Float16)v;
        w1h[i] = *(u16*)&h;
        w1l[i] = f2h(v - (float)h);
    } else {
        int j = i - 98304;
        float v = W2[j];
        _Float16 h = (_Float16)v;
        w2h[j] = *(u16*)&h;
        w2l[j] = f2h(v - (float)h);
    }
}

// ---------------------------------------------------------------------------
// K1: conv1 hh[g][256] = relu(xh @ (w1h+w1l)^T + b1), 2-term f16 MFMA.
// 128 px x 64 cout per block (grid 576 = 2.25/CU); B via global_load_lds
// double-buffer 2x16KB; A = direct s8v loads. XCD swizzle for A-tile L2 reuse.
// Combined reg need ~100 -> fits the 128 cap of (256,4) without spill.
// ---------------------------------------------------------------------------
__global__ __launch_bounds__(256, 4) void k_gemm1(const u16* __restrict__ xh,
                                                  const u16* __restrict__ w1h, const u16* __restrict__ w1l,
                                                  const float* __restrict__ b1,
                                                  u16* __restrict__ hh)
{
    union __align__(16) SM {
        struct { u16 B[2][16][512]; } stg;   // 32 KB staging
        u16 bounce[128 * 66];                // 16.9 KB epilogue transpose
    };
    __shared__ SM sm;
    const int tid = threadIdx.x;
    const int wave = tid >> 6, l = tid & 63, l15 = l & 15, q = l >> 4;
    // swizzle: 576 = 8 xcd x 72; px-group = xcd*18 + k/4, cout-block = k%4
    const int bx = blockIdx.x;
    const int xcd = bx & 7, k = bx >> 3;
    const int g0 = (xcd * 18 + (k >> 2)) * 128;
    const int c0 = (k & 3) * 64;
    const int gw = g0 + wave * 32;

    auto stage = [&](int kt, int buf) {
#pragma unroll
        for (int r = 0; r < 4; ++r) {
            int cid = r * 4 + wave;                 // cid = spl*8 + kf*4 + cs
            int spl = cid >> 3, kf = (cid >> 2) & 1, cs = cid & 3;
            const u16* src = (spl ? w1l : w1h) + (size_t)(c0 + cs * 16 + l15) * 384 + kt + kf * 32 + q * 8;
            __builtin_amdgcn_global_load_lds(
                (const __attribute__((address_space(1))) void*)src,
                (__attribute__((address_space(3))) void*)&sm.stg.B[buf][cid][0],
                16, 0, 0);
        }
    };

    f4v acc[2][4];
#pragma unroll
    for (int s = 0; s < 2; ++s)
#pragma unroll
        for (int c = 0; c < 4; ++c) acc[s][c] = (f4v){0.f, 0.f, 0.f, 0.f};

    stage(0, 0);
    __syncthreads();
    for (int t = 0; t < 6; ++t) {
        const int kt = t * 64;
        const int buf = t & 1;
        if (t < 5) stage(kt + 64, buf ^ 1);
        s8v ah[2][2];
#pragma unroll
        for (int s = 0; s < 2; ++s)
#pragma unroll
            for (int kf = 0; kf < 2; ++kf)
                ah[s][kf] = *(const s8v*)&xh[(size_t)(gw + s * 16 + l15) * 384 + kt + kf * 32 + q * 8];
#pragma unroll
        for (int kf = 0; kf < 2; ++kf)
#pragma unroll
            for (int cs = 0; cs < 4; ++cs) {
                s8v bh = *(const s8v*)&sm.stg.B[buf][kf * 4 + cs][l * 8];
                s8v bl = *(const s8v*)&sm.stg.B[buf][8 + kf * 4 + cs][l * 8];
#pragma unroll
                for (int s = 0; s < 2; ++s) {
                    acc[s][cs] = __builtin_amdgcn_mfma_f32_16x16x32_f16(*(h8v*)&ah[s][kf], *(h8v*)&bh, acc[s][cs], 0, 0, 0);
                    acc[s][cs] = __builtin_amdgcn_mfma_f32_16x16x32_f16(*(h8v*)&ah[s][kf], *(h8v*)&bl, acc[s][cs], 0, 0, 0);
                }
            }
        __syncthreads();
    }

    // epilogue: bias+relu, f16, LDS bounce transpose, coalesced [g][256] store
#pragma unroll
    for (int s = 0; s < 2; ++s)
#pragma unroll
        for (int cs = 0; cs < 4; ++cs) {
            int c = cs * 16 + l15;
            float bv = b1[c0 + c];
#pragma unroll
            for (int r = 0; r < 4; ++r) {
                int px = wave * 32 + s * 16 + q * 4 + r;   // C layout: row=q*4+r, col=l15
                sm.bounce[px * 66 + c] = f2h(fmaxf(acc[s][cs][r] + bv, 0.f));
            }
        }
    __syncthreads();
    {
        int px = tid >> 1, half = tid & 1;
        u32 tmp[16];
#pragma unroll
        for (int j = 0; j < 16; ++j)
            tmp[j] = *(const u32*)&sm.bounce[px * 66 + half * 32 + j * 2];
        size_t o = (size_t)(g0 + px) * 256 + c0 + half * 32;
#pragma unroll
        for (int j = 0; j < 4; ++j)
            *(s8v*)&hh[o + j * 8] = ((s8v*)tmp)[j];
    }
}

// ---------------------------------------------------------------------------
// K2: conv2 feat[g][128] = hh @ (w2h+w2l)^T + b2, 2-term f16 MFMA, fp32 out.
// 128 px x 32 cout per block (grid 576); whole W2 slice staged once (32 KB).
// ---------------------------------------------------------------------------
__global__ __launch_bounds__(256, 4) void k_gemm2(const u16* __restrict__ hh,
                                                  const u16* __restrict__ w2h, const u16* __restrict__ w2l,
                                                  const float* __restrict__ b2,
                                                  float* __restrict__ feat)
{
    __shared__ u16 Bs[32][512];   // 32 KB: cid = spl*16 + kf*2 + cs
    const int tid = threadIdx.x;
    const int wave = tid >> 6, l = tid & 63, l15 = l & 15, q = l >> 4;
    const int bx = blockIdx.x;
    const int xcd = bx & 7, k = bx >> 3;
    const int g0 = (xcd * 18 + (k >> 2)) * 128;
    const int c0 = (k & 3) * 32;

#pragma unroll
    for (int r = 0; r < 8; ++r) {
        int cid = r * 4 + wave;
        int spl = cid >> 4, kf = (cid >> 1) & 7, cs = cid & 1;
        const u16* src = (spl ? w2l : w2h) + (size_t)(c0 + cs * 16 + l15) * 256 + kf * 32 + q * 8;
        __builtin_amdgcn_global_load_lds(
            (const __attribute__((address_space(1))) void*)src,
            (__attribute__((address_space(3))) void*)&Bs[cid][0],
            16, 0, 0);
    }
    __syncthreads();

    const int gw = g0 + wave * 32;
    f4v acc[2][2];
#pragma unroll
    for (int s = 0; s < 2; ++s)
#pragma unroll
        for (int c = 0; c < 2; ++c) acc[s][c] = (f4v){0.f, 0.f, 0.f, 0.f};

#pragma unroll
    for (int kf = 0; kf < 8; ++kf) {
        s8v ah[2];
#pragma unroll
        for (int s = 0; s < 2; ++s)
            ah[s] = *(const s8v*)&hh[(size_t)(gw + s * 16 + l15) * 256 + kf * 32 + q * 8];
#pragma unroll
        for (int cs = 0; cs < 2; ++cs) {
            s8v bh = *(const s8v*)&Bs[kf * 2 + cs][l * 8];
            s8v bl = *(const s8v*)&Bs[16 + kf * 2 + cs][l * 8];
#pragma unroll
            for (int s = 0; s < 2; ++s) {
                acc[s][cs] = __builtin_amdgcn_mfma_f32_16x16x32_f16(*(h8v*)&ah[s], *(h8v*)&bh, acc[s][cs], 0, 0, 0);
                acc[s][cs] = __builtin_amdgcn_mfma_f32_16x16x32_f16(*(h8v*)&ah[s], *(h8v*)&bl, acc[s][cs], 0, 0, 0);
            }
        }
    }
#pragma unroll
    for (int s = 0; s < 2; ++s)
#pragma unroll
        for (int cs = 0; cs < 2; ++cs) {
            float bv = b2[c0 + cs * 16 + l15];
#pragma unroll
            for (int r = 0; r < 4; ++r)
                feat[(size_t)(gw + s * 16 + q * 4 + r) * 128 + c0 + cs * 16 + l15] = acc[s][cs][r] + bv;
        }
}

// ---------------------------------------------------------------------------
// K3: normalize rows of feat [g][128] -> rf fp32 + bf16 hi. 32 px/block.
// ---------------------------------------------------------------------------
__global__ __launch_bounds__(256) void k_norm2(const float* __restrict__ feat,
                                               float* __restrict__ rf,
                                               u16* __restrict__ hib)
{
    const int tid = threadIdx.x;
    const int px = blockIdx.x * 32 + (tid >> 3), part = tid & 7;
    const size_t o = (size_t)px * 128 + part * 16;
    f4v v[4];
    float ss = 0.f;
#pragma unroll
    for (int j = 0; j < 4; ++j) {
        v[j] = *(const f4v*)&feat[o + j * 4];
        ss += v[j][0]*v[j][0] + v[j][1]*v[j][1] + v[j][2]*v[j][2] + v[j][3]*v[j][3];
    }
    ss += __shfl_xor(ss, 1, 64);
    ss += __shfl_xor(ss, 2, 64);
    ss += __shfl_xor(ss, 4, 64);
    const float mx = fmaxf(sqrtf(ss), 1e-12f);
    u16 hb[16];
#pragma unroll
    for (int j = 0; j < 4; ++j) {
        f4v w;
#pragma unroll
        for (int e = 0; e < 4; ++e) {
            float val = v[j][e] / mx;
            w[e] = val;
            hb[j * 4 + e] = f2bf(val);
        }
        *(f4v*)&rf[o + j * 4] = w;
    }
    *(s8v*)&hib[o]     = *(s8v*)&hb[0];
    *(s8v*)&hib[o + 8] = *(s8v*)&hb[8];
}

// ---------------------------------------------------------------------------
// K4: sim selection via 1-term bf16 MFMA + sortable-key argmax (R8-proven).
// NOTE: combined reg footprint ~172 (108 VGPR + 64 AGPR) -> ONLY fits
// 2 waves/SIMD. (256,4) caused total spill in R10 (VGPR capped 64,
// WRITE_SIZE 229 MB, 235 us). Keep (256,2).
// ---------------------------------------------------------------------------
__global__ __launch_bounds__(256, 2) void k_simtop(const u16* __restrict__ hi,
                                                   int* __restrict__ cidx)
{
    __shared__ u16 Bs[2][16][512];
    const int tid  = threadIdx.x;
    const int wave = tid >> 6, l = tid & 63, l15 = l & 15, q = l >> 4;
    const int b     = blockIdx.z;
    const int rbase = blockIdx.x * 256;
    const int chunk = blockIdx.y;
    const int cbase = chunk * 576;
    const size_t base = (size_t)b * NHW;
    const int wr0 = rbase + wave * 64;

    s8v ah[4][4];
#pragma unroll
    for (int s = 0; s < 4; ++s) {
        int row = wr0 + s * 16 + l15;
#pragma unroll
        for (int kf = 0; kf < 4; ++kf)
            ah[s][kf] = *(const s8v*)&hi[(base + row) * 128 + kf * 32 + q * 8];
    }

    auto stage = [&](int colt, int buf) {
#pragma unroll
        for (int r = 0; r < 4; ++r) {
            int cid = r * 4 + wave;
            int kf = cid >> 2, cs = cid & 3;
            int col = colt + cs * 16 + l15;
            const u16* src = hi + (base + col) * 128 + kf * 32 + q * 8;
            __builtin_amdgcn_global_load_lds(
                (const __attribute__((address_space(1))) void*)src,
                (__attribute__((address_space(3))) void*)&Bs[buf][cid][0],
                16, 0, 0);
        }
    };

    u32 bk[4][4];
#pragma unroll
    for (int s = 0; s < 4; ++s)
#pragma unroll
        for (int r = 0; r < 4; ++r) bk[s][r] = 0u;

    stage(cbase, 0);
    __syncthreads();

    for (int ct = 0; ct < 9; ++ct) {
        const int colt = cbase + ct * 64;
        const int buf  = ct & 1;
        if (ct < 8) stage(colt + 64, buf ^ 1);

        f4v acc[4][4];
#pragma unroll
        for (int s = 0; s < 4; ++s)
#pragma unroll
            for (int c = 0; c < 4; ++c) acc[s][c] = (f4v){2.f, 2.f, 2.f, 2.f};

#pragma unroll
        for (int kf = 0; kf < 4; ++kf)
#pragma unroll
            for (int cs = 0; cs < 4; ++cs) {
                s8v bh = *(const s8v*)&Bs[buf][kf * 4 + cs][l * 8];
#pragma unroll
                for (int s = 0; s < 4; ++s)
                    acc[s][cs] = __builtin_amdgcn_mfma_f32_16x16x32_bf16(ah[s][kf], bh, acc[s][cs], 0, 0, 0);
            }

        const u32 tagv = (u32)(ct << 2);
        const bool hasdiag = (colt < wr0 + 64) && (wr0 < colt + 64);
        if (hasdiag) {
#pragma unroll
            for (int s = 0; s < 4; ++s)
#pragma unroll
                for (int r = 0; r < 4; ++r) {
                    const int rr = wr0 + s * 16 + q * 4 + r;
                    u32 km = 0u;
#pragma unroll
                    for (int cs = 0; cs < 4; ++cs) {
                        u32 kk = (__float_as_uint(acc[s][cs][r]) & 0xffffffc0u) | (tagv | (u32)cs);
                        if (colt + cs * 16 + l15 == rr) kk = 0u;
                        km = kk > km ? kk : km;
                    }
                    bk[s][r] = km > bk[s][r] ? km : bk[s][r];
                }
        } else {
#pragma unroll
            for (int s = 0; s < 4; ++s)
#pragma unroll
                for (int r = 0; r < 4; ++r) {
                    u32 km = 0u;
#pragma unroll
                    for (int cs = 0; cs < 4; ++cs) {
                        u32 kk = (__float_as_uint(acc[s][cs][r]) & 0xffffffc0u) | (tagv | (u32)cs);
                        km = kk > km ? kk : km;
                    }
                    bk[s][r] = km > bk[s][r] ? km : bk[s][r];
                }
        }
        __syncthreads();
    }

#pragma unroll
    for (int s = 0; s < 4; ++s)
#pragma unroll
        for (int r = 0; r < 4; ++r) {
            u32 key = bk[s][r];
            float v = __uint_as_float(key & 0xffffffc0u);
            int ctw = (int)((key >> 2) & 15u);
            int csw = (int)(key & 3u);
            int col = cbase + ctw * 64 + csw * 16 + l15;
#pragma unroll
            for (int d = 1; d < 16; d <<= 1) {
                float ov = __shfl_xor(v, d, 64);
                int   oi = __shfl_xor(col, d, 64);
                bool p = (ov > v) || (ov == v && oi < col);
                v   = p ? ov : v;
                col = p ? oi : col;
            }
            if (l15 == 0) {
                int row = wr0 + s * 16 + q * 4 + r;
                cidx[(base + row) * NCHUNK + chunk] = col;
            }
        }
}

// ---------------------------------------------------------------------------
// K5: exact fp32 re-rank of 16 candidates + distance + mask (R8-proven)
// ---------------------------------------------------------------------------
__global__ __launch_bounds__(256) void k_finish(const float* __restrict__ rf,
                                                const int* __restrict__ cidx,
                                                float* __restrict__ out)
{
    const int tid = threadIdx.x;
    const int g = blockIdx.x * 16 + (tid >> 4);
    const int l15 = tid & 15;
    const int b = g / NHW;
    const size_t rowbase = (size_t)b * NHW;

    const float* x = rf + (size_t)g * 128;
    f4v x0 = *(const f4v*)&x[l15 * 8];
    f4v x1 = *(const f4v*)&x[l15 * 8 + 4];

    float bestS = -2.f; int bestI = 0;
#pragma unroll
    for (int j = 0; j < NCHUNK; ++j) {
        int c = cidx[(size_t)g * NCHUNK + j];
        const float* y = rf + (rowbase + c) * 128;
        f4v y0 = *(const f4v*)&y[l15 * 8];
        f4v y1 = *(const f4v*)&y[l15 * 8 + 4];
        float s = x0[0]*y0[0] + x0[1]*y0[1] + x0[2]*y0[2] + x0[3]*y0[3]
                + x1[0]*y1[0] + x1[1]*y1[1] + x1[2]*y1[2] + x1[3]*y1[3];
#pragma unroll
        for (int d = 1; d < 16; d <<= 1) s += __shfl_xor(s, d, 64);
        bool p = (s > bestS) || (s == bestS && c < bestI);
        bestS = p ? s : bestS;
        bestI = p ? c : bestI;
    }

    const float* y = rf + (rowbase + bestI) * 128;
    f4v y0 = *(const f4v*)&y[l15 * 8];
    f4v y1 = *(const f4v*)&y[l15 * 8 + 4];
    float d0 = x0[0]-y0[0], d1 = x0[1]-y0[1], d2 = x0[2]-y0[2], d3 = x0[3]-y0[3];
    float e0 = x1[0]-y1[0], e1 = x1[1]-y1[1], e2 = x1[2]-y1[2], e3 = x1[3]-y1[3];
    float ss = d0*d0 + d1*d1 + d2*d2 + d3*d3 + e0*e0 + e1*e1 + e2*e2 + e3*e3;
#pragma unroll
    for (int d = 1; d < 16; d <<= 1) ss += __shfl_xor(ss, d, 64);
    if (l15 == 0) {
        float dist = sqrtf(ss);
        out[NB * NHW + g] = dist;
        out[g] = dist > 0.2f ? 1.0f : 0.0f;
    }
}

// ===========================================================================
extern "C" void kernel_launch(void* const* d_in, const int* in_sizes, int n_in,
                              void* d_out, int out_size, void* d_ws, size_t ws_size,
                              hipStream_t stream) {
    const float* features = (const float*)d_in[0];
    const float* W1 = (const float*)d_in[1];
    const float* b1 = (const float*)d_in[2];
    const float* W2 = (const float*)d_in[3];
    const float* b2 = (const float*)d_in[4];
    float* out = (float*)d_out;
    float* ws  = (float*)d_ws;

    // ws layout (float offsets), peak 6,029,312 f = 24.1 MB:
    //   [0,       3538944)  xh (18432x384 f16)  -> after gemm1: feat + hib
    //   [3538944, 5898240)  hh (18432x256 f16)  -> after gemm2: rf
    //   [5898240, 6029312)  w1h/w1l/w2h/w2l
    //   cidx aliases feat [0, 294912) after norm2.
    u16*   xh   = (u16*)ws;
    u16*   hh   = (u16*)(ws + 3538944);
    u16*   w1h  = (u16*)(ws + 5898240);
    u16*   w1l  = (u16*)(ws + 5947392);
    u16*   w2h  = (u16*)(ws + 5996544);
    u16*   w2l  = (u16*)(ws + 6012928);
    float* feat = ws;
    u16*   hib  = (u16*)(ws + 2359296);
    float* rf   = ws + 3538944;
    int*   cidx = (int*)ws;

    // transpose + f16 split of X (3 passes/block); weight splits
    k_xsplit<<<dim3(144, 2, NB), 256, 0, stream>>>(features, xh);
    k_wsplit<<<512, 256, 0, stream>>>(W1, W2, w1h, w1l, w2h, w2l);
    // conv1 (2-term f16 MFMA, 128px x 64cout, XCD-swizzled)
    k_gemm1<<<576, 256, 0, stream>>>(xh, w1h, w1l, b1, hh);
    // conv2 (2-term f16 MFMA, 128px x 32cout, XCD-swizzled)
    k_gemm2<<<576, 256, 0, stream>>>(hh, w2h, w2l, b2, feat);
    // L2 normalize + bf16 hi (32 px/block)
    k_norm2<<<576, 256, 0, stream>>>(feat, rf, hib);
    // 1-term bf16 sim selection: per-chunk argmax candidates
    k_simtop<<<dim3(36, NCHUNK, NB), 256, 0, stream>>>(hib, cidx);
    // exact fp32 re-rank of 16 candidates + distance + mask
    k_finish<<<1152, 256, 0, stream>>>(rf, cidx, out);
}

// Round 12
// 187.009 us; speedup vs baseline: 1.8264x; 1.0831x over previous
//
#include <hip/hip_runtime.h>

#define NHW 9216   // 96*96
#define NB 2
#define NCHUNK 16  // col chunks for k_simtop

typedef short s8v __attribute__((ext_vector_type(8)));       // 8x16-bit in 4 VGPRs
typedef _Float16 h8v __attribute__((ext_vector_type(8)));    // 8 f16
typedef float f4v __attribute__((ext_vector_type(4)));
typedef unsigned int u32;
typedef unsigned short u16;

__device__ inline u16 f2bf(float x) {
    u32 u = __float_as_uint(x);
    u += 0x7fffu + ((u >> 16) & 1u);          // round-to-nearest-even
    return (u16)(u >> 16);
}
__device__ inline u16 f2h(float x) {
    _Float16 h = (_Float16)x;
    return *(u16*)&h;
}

// ---------------------------------------------------------------------------
// K0a: transpose X [b][384][9216] fp32 -> xh f16 [g][384]. 3 passes/block.
// ---------------------------------------------------------------------------
__global__ __launch_bounds__(256) void k_xsplit(const float* __restrict__ X,
                                                u16* __restrict__ xh)
{
    __shared__ float fs[64][65];
    const int tid = threadIdx.x;
    const int b = blockIdx.z, p0 = blockIdx.x * 64, half = blockIdx.y;
    const size_t fb = (size_t)b * 384 * NHW;
    const int px = tid >> 2, sub = tid & 3;
    const size_t g = (size_t)b * NHW + p0 + px;
    for (int pass = half * 3; pass < half * 3 + 3; ++pass) {
        int c0p = pass * 64;
        __syncthreads();
#pragma unroll
        for (int r = 0; r < 16; ++r) {
            int e = r * 256 + tid;
            int cc = e >> 6, p = e & 63;
            fs[cc][p] = X[fb + (size_t)(c0p + cc) * NHW + p0 + p];
        }
        __syncthreads();
        u16 hb[16];
#pragma unroll
        for (int i = 0; i < 16; ++i) hb[i] = f2h(fs[sub * 16 + i][px]);
        size_t o = g * 384 + c0p + sub * 16;
        *(s8v*)&xh[o]     = *(s8v*)&hb[0];
        *(s8v*)&xh[o + 8] = *(s8v*)&hb[8];
    }
}

// ---------------------------------------------------------------------------
// K0b: W1 -> f16 hi/lo; W2 -> f16 hi only (conv2 is 1-term now)
// ---------------------------------------------------------------------------
__global__ __launch_bounds__(256) void k_wsplit(const float* __restrict__ W1,
                                                const float* __restrict__ W2,
                                                u16* __restrict__ w1h, u16* __restrict__ w1l,
                                                u16* __restrict__ w2h)
{
    int i = blockIdx.x * 256 + threadIdx.x;
    if (i < 98304) {
        float v = W1[i];
        _Float16 h = (_Float16)v;
        w1h[i] = *(u16*)&h;
        w1l[i] = f2h(v - (float)h);
    } else {
        int j = i - 98304;
        w2h[j] = f2h(W2[j]);
    }
}

// ---------------------------------------------------------------------------
// K1: conv1 hh[g][256] = relu(xh @ (w1h+w1l)^T + b1), 2-term f16 MFMA.
// 128 px x 64 cout per block (grid 576); double-buffered global_load_lds.
// ---------------------------------------------------------------------------
__global__ __launch_bounds__(256, 4) void k_gemm1(const u16* __restrict__ xh,
                                                  const u16* __restrict__ w1h, const u16* __restrict__ w1l,
                                                  const float* __restrict__ b1,
                                                  u16* __restrict__ hh)
{
    union __align__(16) SM {
        struct { u16 B[2][16][512]; } stg;   // 32 KB staging
        u16 bounce[128 * 66];                // 16.9 KB epilogue transpose
    };
    __shared__ SM sm;
    const int tid = threadIdx.x;
    const int wave = tid >> 6, l = tid & 63, l15 = l & 15, q = l >> 4;
    const int bx = blockIdx.x;
    const int xcd = bx & 7, k = bx >> 3;
    const int g0 = (xcd * 18 + (k >> 2)) * 128;
    const int c0 = (k & 3) * 64;
    const int gw = g0 + wave * 32;

    auto stage = [&](int kt, int buf) {
#pragma unroll
        for (int r = 0; r < 4; ++r) {
            int cid = r * 4 + wave;                 // cid = spl*8 + kf*4 + cs
            int spl = cid >> 3, kf = (cid >> 2) & 1, cs = cid & 3;
            const u16* src = (spl ? w1l : w1h) + (size_t)(c0 + cs * 16 + l15) * 384 + kt + kf * 32 + q * 8;
            __builtin_amdgcn_global_load_lds(
                (const __attribute__((address_space(1))) void*)src,
                (__attribute__((address_space(3))) void*)&sm.stg.B[buf][cid][0],
                16, 0, 0);
        }
    };

    f4v acc[2][4];
#pragma unroll
    for (int s = 0; s < 2; ++s)
#pragma unroll
        for (int c = 0; c < 4; ++c) acc[s][c] = (f4v){0.f, 0.f, 0.f, 0.f};

    stage(0, 0);
    __syncthreads();
    for (int t = 0; t < 6; ++t) {
        const int kt = t * 64;
        const int buf = t & 1;
        if (t < 5) stage(kt + 64, buf ^ 1);
        s8v ah[2][2];
#pragma unroll
        for (int s = 0; s < 2; ++s)
#pragma unroll
            for (int kf = 0; kf < 2; ++kf)
                ah[s][kf] = *(const s8v*)&xh[(size_t)(gw + s * 16 + l15) * 384 + kt + kf * 32 + q * 8];
#pragma unroll
        for (int kf = 0; kf < 2; ++kf)
#pragma unroll
            for (int cs = 0; cs < 4; ++cs) {
                s8v bh = *(const s8v*)&sm.stg.B[buf][kf * 4 + cs][l * 8];
                s8v bl = *(const s8v*)&sm.stg.B[buf][8 + kf * 4 + cs][l * 8];
#pragma unroll
                for (int s = 0; s < 2; ++s) {
                    acc[s][cs] = __builtin_amdgcn_mfma_f32_16x16x32_f16(*(h8v*)&ah[s][kf], *(h8v*)&bh, acc[s][cs], 0, 0, 0);
                    acc[s][cs] = __builtin_amdgcn_mfma_f32_16x16x32_f16(*(h8v*)&ah[s][kf], *(h8v*)&bl, acc[s][cs], 0, 0, 0);
                }
            }
        __syncthreads();
    }

    // epilogue: bias+relu, f16, LDS bounce transpose, coalesced [g][256] store
#pragma unroll
    for (int s = 0; s < 2; ++s)
#pragma unroll
        for (int cs = 0; cs < 4; ++cs) {
            int c = cs * 16 + l15;
            float bv = b1[c0 + c];
#pragma unroll
            for (int r = 0; r < 4; ++r) {
                int px = wave * 32 + s * 16 + q * 4 + r;
                sm.bounce[px * 66 + c] = f2h(fmaxf(acc[s][cs][r] + bv, 0.f));
            }
        }
    __syncthreads();
    {
        int px = tid >> 1, half = tid & 1;
        u32 tmp[16];
#pragma unroll
        for (int j = 0; j < 16; ++j)
            tmp[j] = *(const u32*)&sm.bounce[px * 66 + half * 32 + j * 2];
        size_t o = (size_t)(g0 + px) * 256 + c0 + half * 32;
#pragma unroll
        for (int j = 0; j < 4; ++j)
            *(s8v*)&hh[o + j * 8] = ((s8v*)tmp)[j];
    }
}

// ---------------------------------------------------------------------------
// K2: FUSED conv2 + L2-normalize. Block = 64 px x ALL 128 couts (wave = 16 px),
// W2 hi staged once (exactly 64 KB LDS, R5-proven size), 1-term f16 MFMA.
// Epilogue: bias, row sum-of-squares via cross-lane reduce, write rf + hib.
// No feat round-trip to HBM.
// ---------------------------------------------------------------------------
__global__ __launch_bounds__(256) void k_gemm2n(const u16* __restrict__ hh,
                                                const u16* __restrict__ w2h,
                                                const float* __restrict__ b2,
                                                float* __restrict__ rf,
                                                u16* __restrict__ hib)
{
    __shared__ u16 Bs[64][512];   // 64 KB: cid = kf*8 + cst
    const int tid = threadIdx.x;
    const int wave = tid >> 6, l = tid & 63, l15 = l & 15, q = l >> 4;
    const int bx = blockIdx.x;
    const int xcd = bx & 7, k = bx >> 3;
    const int g0 = (xcd * 36 + k) * 64;

#pragma unroll
    for (int r = 0; r < 16; ++r) {
        int cid = r * 4 + wave;
        int kf = cid >> 3, cst = cid & 7;
        const u16* src = w2h + (size_t)(cst * 16 + l15) * 256 + kf * 32 + q * 8;
        __builtin_amdgcn_global_load_lds(
            (const __attribute__((address_space(1))) void*)src,
            (__attribute__((address_space(3))) void*)&Bs[cid][0],
            16, 0, 0);
    }
    __syncthreads();

    const int gw = g0 + wave * 16;
    f4v acc[8];
#pragma unroll
    for (int c = 0; c < 8; ++c) acc[c] = (f4v){0.f, 0.f, 0.f, 0.f};

#pragma unroll
    for (int kf = 0; kf < 8; ++kf) {
        s8v ah = *(const s8v*)&hh[(size_t)(gw + l15) * 256 + kf * 32 + q * 8];
#pragma unroll
        for (int cst = 0; cst < 8; ++cst) {
            s8v bh = *(const s8v*)&Bs[kf * 8 + cst][l * 8];
            acc[cst] = __builtin_amdgcn_mfma_f32_16x16x32_f16(*(h8v*)&ah, *(h8v*)&bh, acc[cst], 0, 0, 0);
        }
    }

    // bias + per-row sum of squares (row = gw + q*4 + r; its 128 ch live in
    // 8 cst tiles x 16 l15 lanes, same q group -> shfl_xor d<16 stays in group)
    float ssq[4] = {0.f, 0.f, 0.f, 0.f};
#pragma unroll
    for (int cst = 0; cst < 8; ++cst) {
        float bv = b2[cst * 16 + l15];
#pragma unroll
        for (int r = 0; r < 4; ++r) {
            acc[cst][r] += bv;
            ssq[r] += acc[cst][r] * acc[cst][r];
        }
    }
#pragma unroll
    for (int r = 0; r < 4; ++r) {
        ssq[r] += __shfl_xor(ssq[r], 1, 64);
        ssq[r] += __shfl_xor(ssq[r], 2, 64);
        ssq[r] += __shfl_xor(ssq[r], 4, 64);
        ssq[r] += __shfl_xor(ssq[r], 8, 64);
        ssq[r] = 1.0f / fmaxf(sqrtf(ssq[r]), 1e-12f);
    }
#pragma unroll
    for (int cst = 0; cst < 8; ++cst)
#pragma unroll
        for (int r = 0; r < 4; ++r) {
            float val = acc[cst][r] * ssq[r];
            size_t o = (size_t)(gw + q * 4 + r) * 128 + cst * 16 + l15;
            rf[o]  = val;
            hib[o] = f2bf(val);
        }
}

// ---------------------------------------------------------------------------
// K3: sim selection via 1-term bf16 MFMA + sortable-key argmax.
// R12: s=3 (48 rows/wave, 192/block) -> combined regs ~136 fits 3 blocks/CU
// (cap 170 at (256,3)). Grid 48x16x2 = 1536 = 6/CU even.
// NOTE: s=4 variant needs ~172 combined -> only 2/CU; (256,4) spilled (R10).
// ---------------------------------------------------------------------------
__global__ __launch_bounds__(256, 3) void k_simtop(const u16* __restrict__ hi,
                                                   int* __restrict__ cidx)
{
    __shared__ u16 Bs[2][16][512];
    const int tid  = threadIdx.x;
    const int wave = tid >> 6, l = tid & 63, l15 = l & 15, q = l >> 4;
    const int b     = blockIdx.z;
    const int rbase = blockIdx.x * 192;
    const int chunk = blockIdx.y;
    const int cbase = chunk * 576;
    const size_t base = (size_t)b * NHW;
    const int wr0 = rbase + wave * 48;

    s8v ah[3][4];
#pragma unroll
    for (int s = 0; s < 3; ++s) {
        int row = wr0 + s * 16 + l15;
#pragma unroll
        for (int kf = 0; kf < 4; ++kf)
            ah[s][kf] = *(const s8v*)&hi[(base + row) * 128 + kf * 32 + q * 8];
    }

    auto stage = [&](int colt, int buf) {
#pragma unroll
        for (int r = 0; r < 4; ++r) {
            int cid = r * 4 + wave;
            int kf = cid >> 2, cs = cid & 3;
            int col = colt + cs * 16 + l15;
            const u16* src = hi + (base + col) * 128 + kf * 32 + q * 8;
            __builtin_amdgcn_global_load_lds(
                (const __attribute__((address_space(1))) void*)src,
                (__attribute__((address_space(3))) void*)&Bs[buf][cid][0],
                16, 0, 0);
        }
    };

    u32 bk[3][4];
#pragma unroll
    for (int s = 0; s < 3; ++s)
#pragma unroll
        for (int r = 0; r < 4; ++r) bk[s][r] = 0u;

    stage(cbase, 0);
    __syncthreads();

    for (int ct = 0; ct < 9; ++ct) {
        const int colt = cbase + ct * 64;
        const int buf  = ct & 1;
        if (ct < 8) stage(colt + 64, buf ^ 1);

        f4v acc[3][4];
#pragma unroll
        for (int s = 0; s < 3; ++s)
#pragma unroll
            for (int c = 0; c < 4; ++c) acc[s][c] = (f4v){2.f, 2.f, 2.f, 2.f};

#pragma unroll
        for (int kf = 0; kf < 4; ++kf)
#pragma unroll
            for (int cs = 0; cs < 4; ++cs) {
                s8v bh = *(const s8v*)&Bs[buf][kf * 4 + cs][l * 8];
#pragma unroll
                for (int s = 0; s < 3; ++s)
                    acc[s][cs] = __builtin_amdgcn_mfma_f32_16x16x32_bf16(ah[s][kf], bh, acc[s][cs], 0, 0, 0);
            }

        const u32 tagv = (u32)(ct << 2);
        const bool hasdiag = (colt < wr0 + 48) && (wr0 < colt + 64);
        if (hasdiag) {
#pragma unroll
            for (int s = 0; s < 3; ++s)
#pragma unroll
                for (int r = 0; r < 4; ++r) {
                    const int rr = wr0 + s * 16 + q * 4 + r;
                    u32 km = 0u;
#pragma unroll
                    for (int cs = 0; cs < 4; ++cs) {
                        u32 kk = (__float_as_uint(acc[s][cs][r]) & 0xffffffc0u) | (tagv | (u32)cs);
                        if (colt + cs * 16 + l15 == rr) kk = 0u;
                        km = kk > km ? kk : km;
                    }
                    bk[s][r] = km > bk[s][r] ? km : bk[s][r];
                }
        } else {
#pragma unroll
            for (int s = 0; s < 3; ++s)
#pragma unroll
                for (int r = 0; r < 4; ++r) {
                    u32 km = 0u;
#pragma unroll
                    for (int cs = 0; cs < 4; ++cs) {
                        u32 kk = (__float_as_uint(acc[s][cs][r]) & 0xffffffc0u) | (tagv | (u32)cs);
                        km = kk > km ? kk : km;
                    }
                    bk[s][r] = km > bk[s][r] ? km : bk[s][r];
                }
        }
        __syncthreads();
    }

#pragma unroll
    for (int s = 0; s < 3; ++s)
#pragma unroll
        for (int r = 0; r < 4; ++r) {
            u32 key = bk[s][r];
            float v = __uint_as_float(key & 0xffffffc0u);
            int ctw = (int)((key >> 2) & 15u);
            int csw = (int)(key & 3u);
            int col = cbase + ctw * 64 + csw * 16 + l15;
#pragma unroll
            for (int d = 1; d < 16; d <<= 1) {
                float ov = __shfl_xor(v, d, 64);
                int   oi = __shfl_xor(col, d, 64);
                bool p = (ov > v) || (ov == v && oi < col);
                v   = p ? ov : v;
                col = p ? oi : col;
            }
            if (l15 == 0) {
                int row = wr0 + s * 16 + q * 4 + r;
                cidx[(base + row) * NCHUNK + chunk] = col;
            }
        }
}

// ---------------------------------------------------------------------------
// K4: exact fp32 re-rank of 16 candidates + distance + mask (R8-proven)
// ---------------------------------------------------------------------------
__global__ __launch_bounds__(256) void k_finish(const float* __restrict__ rf,
                                                const int* __restrict__ cidx,
                                                float* __restrict__ out)
{
    const int tid = threadIdx.x;
    const int g = blockIdx.x * 16 + (tid >> 4);
    const int l15 = tid & 15;
    const int b = g / NHW;
    const size_t rowbase = (size_t)b * NHW;

    const float* x = rf + (size_t)g * 128;
    f4v x0 = *(const f4v*)&x[l15 * 8];
    f4v x1 = *(const f4v*)&x[l15 * 8 + 4];

    float bestS = -2.f; int bestI = 0;
#pragma unroll
    for (int j = 0; j < NCHUNK; ++j) {
        int c = cidx[(size_t)g * NCHUNK + j];
        const float* y = rf + (rowbase + c) * 128;
        f4v y0 = *(const f4v*)&y[l15 * 8];
        f4v y1 = *(const f4v*)&y[l15 * 8 + 4];
        float s = x0[0]*y0[0] + x0[1]*y0[1] + x0[2]*y0[2] + x0[3]*y0[3]
                + x1[0]*y1[0] + x1[1]*y1[1] + x1[2]*y1[2] + x1[3]*y1[3];
#pragma unroll
        for (int d = 1; d < 16; d <<= 1) s += __shfl_xor(s, d, 64);
        bool p = (s > bestS) || (s == bestS && c < bestI);
        bestS = p ? s : bestS;
        bestI = p ? c : bestI;
    }

    const float* y = rf + (rowbase + bestI) * 128;
    f4v y0 = *(const f4v*)&y[l15 * 8];
    f4v y1 = *(const f4v*)&y[l15 * 8 + 4];
    float d0 = x0[0]-y0[0], d1 = x0[1]-y0[1], d2 = x0[2]-y0[2], d3 = x0[3]-y0[3];
    float e0 = x1[0]-y1[0], e1 = x1[1]-y1[1], e2 = x1[2]-y1[2], e3 = x1[3]-y1[3];
    float ss = d0*d0 + d1*d1 + d2*d2 + d3*d3 + e0*e0 + e1*e1 + e2*e2 + e3*e3;
#pragma unroll
    for (int d = 1; d < 16; d <<= 1) ss += __shfl_xor(ss, d, 64);
    if (l15 == 0) {
        float dist = sqrtf(ss);
        out[NB * NHW + g] = dist;
        out[g] = dist > 0.2f ? 1.0f : 0.0f;
    }
}

// ===========================================================================
extern "C" void kernel_launch(void* const* d_in, const int* in_sizes, int n_in,
                              void* d_out, int out_size, void* d_ws, size_t ws_size,
                              hipStream_t stream) {
    const float* features = (const float*)d_in[0];
    const float* W1 = (const float*)d_in[1];
    const float* b1 = (const float*)d_in[2];
    const float* W2 = (const float*)d_in[3];
    const float* b2 = (const float*)d_in[4];
    float* out = (float*)d_out;
    float* ws  = (float*)d_ws;

    // ws layout (float offsets), peak 6,029,312 f = 24.1 MB:
    //   [0,       3538944)  xh (18432x384 f16)  -> after gemm1: rf [0,2359296) + hib [2359296,3538944)
    //   [3538944, 5898240)  hh (18432x256 f16)  -> after gemm2n: cidx
    //   [5898240, 6012928)  w1h/w1l/w2h
    u16*   xh   = (u16*)ws;
    u16*   hh   = (u16*)(ws + 3538944);
    u16*   w1h  = (u16*)(ws + 5898240);
    u16*   w1l  = (u16*)(ws + 5947392);
    u16*   w2h  = (u16*)(ws + 5996544);
    float* rf   = ws;
    u16*   hib  = (u16*)(ws + 2359296);
    int*   cidx = (int*)(ws + 3538944);

    // transpose + f16 split of X; weight splits (W2 hi-only)
    k_xsplit<<<dim3(144, 2, NB), 256, 0, stream>>>(features, xh);
    k_wsplit<<<512, 256, 0, stream>>>(W1, W2, w1h, w1l, w2h);
    // conv1 (2-term f16 MFMA, 128px x 64cout, XCD-swizzled)
    k_gemm1<<<576, 256, 0, stream>>>(xh, w1h, w1l, b1, hh);
    // fused conv2 + normalize (1-term f16 MFMA, 64px x 128cout)
    k_gemm2n<<<288, 256, 0, stream>>>(hh, w2h, b2, rf, hib);
    // 1-term bf16 sim selection (s=3, 3 blocks/CU, grid 6/CU even)
    k_simtop<<<dim3(48, NCHUNK, NB), 256, 0, stream>>>(hib, cidx);
    // exact fp32 re-rank of 16 candidates + distance + mask
    k_finish<<<1152, 256, 0, stream>>>(rf, cidx, out);
}

// Round 13
// 164.393 us; speedup vs baseline: 2.0776x; 1.1376x over previous
//
#include <hip/hip_runtime.h>

#define NHW 9216   // 96*96
#define NB 2
#define NCHUNK 16  // col chunks for k_simtop

typedef short s8v __attribute__((ext_vector_type(8)));       // 8x16-bit in 4 VGPRs
typedef _Float16 h8v __attribute__((ext_vector_type(8)));    // 8 f16
typedef float f4v __attribute__((ext_vector_type(4)));
typedef int i4v __attribute__((ext_vector_type(4)));         // 16 i8 / 4 i32
typedef unsigned int u32;
typedef unsigned short u16;

#define QSCALE 181.0f   // 127/0.7 — |rf elem| > 0.7 has ~0 probability for unit rows
#define IBIAS  2097152  // 2^21 > max |int sim| = 128*127*127 = 2,064,512

__device__ inline u16 f2h(float x) {
    _Float16 h = (_Float16)x;
    return *(u16*)&h;
}

// ---------------------------------------------------------------------------
// K0a: transpose X [b][384][9216] fp32 -> xh f16 [g][384]. 3 passes/block.
// ---------------------------------------------------------------------------
__global__ __launch_bounds__(256) void k_xsplit(const float* __restrict__ X,
                                                u16* __restrict__ xh)
{
    __shared__ float fs[64][65];
    const int tid = threadIdx.x;
    const int b = blockIdx.z, p0 = blockIdx.x * 64, half = blockIdx.y;
    const size_t fb = (size_t)b * 384 * NHW;
    const int px = tid >> 2, sub = tid & 3;
    const size_t g = (size_t)b * NHW + p0 + px;
    for (int pass = half * 3; pass < half * 3 + 3; ++pass) {
        int c0p = pass * 64;
        __syncthreads();
#pragma unroll
        for (int r = 0; r < 16; ++r) {
            int e = r * 256 + tid;
            int cc = e >> 6, p = e & 63;
            fs[cc][p] = X[fb + (size_t)(c0p + cc) * NHW + p0 + p];
        }
        __syncthreads();
        u16 hb[16];
#pragma unroll
        for (int i = 0; i < 16; ++i) hb[i] = f2h(fs[sub * 16 + i][px]);
        size_t o = g * 384 + c0p + sub * 16;
        *(s8v*)&xh[o]     = *(s8v*)&hb[0];
        *(s8v*)&xh[o + 8] = *(s8v*)&hb[8];
    }
}

// ---------------------------------------------------------------------------
// K0b: W1 -> f16 hi/lo; W2 -> f16 hi only
// ---------------------------------------------------------------------------
__global__ __launch_bounds__(256) void k_wsplit(const float* __restrict__ W1,
                                                const float* __restrict__ W2,
                                                u16* __restrict__ w1h, u16* __restrict__ w1l,
                                                u16* __restrict__ w2h)
{
    int i = blockIdx.x * 256 + threadIdx.x;
    if (i < 98304) {
        float v = W1[i];
        _Float16 h = (_Float16)v;
        w1h[i] = *(u16*)&h;
        w1l[i] = f2h(v - (float)h);
    } else {
        int j = i - 98304;
        w2h[j] = f2h(W2[j]);
    }
}

// ---------------------------------------------------------------------------
// K1: conv1 hh[g][256] = relu(xh @ (w1h+w1l)^T + b1), 2-term f16 MFMA. (R12)
// ---------------------------------------------------------------------------
__global__ __launch_bounds__(256, 4) void k_gemm1(const u16* __restrict__ xh,
                                                  const u16* __restrict__ w1h, const u16* __restrict__ w1l,
                                                  const float* __restrict__ b1,
                                                  u16* __restrict__ hh)
{
    union __align__(16) SM {
        struct { u16 B[2][16][512]; } stg;   // 32 KB staging
        u16 bounce[128 * 66];                // 16.9 KB epilogue transpose
    };
    __shared__ SM sm;
    const int tid = threadIdx.x;
    const int wave = tid >> 6, l = tid & 63, l15 = l & 15, q = l >> 4;
    const int bx = blockIdx.x;
    const int xcd = bx & 7, k = bx >> 3;
    const int g0 = (xcd * 18 + (k >> 2)) * 128;
    const int c0 = (k & 3) * 64;
    const int gw = g0 + wave * 32;

    auto stage = [&](int kt, int buf) {
#pragma unroll
        for (int r = 0; r < 4; ++r) {
            int cid = r * 4 + wave;                 // cid = spl*8 + kf*4 + cs
            int spl = cid >> 3, kf = (cid >> 2) & 1, cs = cid & 3;
            const u16* src = (spl ? w1l : w1h) + (size_t)(c0 + cs * 16 + l15) * 384 + kt + kf * 32 + q * 8;
            __builtin_amdgcn_global_load_lds(
                (const __attribute__((address_space(1))) void*)src,
                (__attribute__((address_space(3))) void*)&sm.stg.B[buf][cid][0],
                16, 0, 0);
        }
    };

    f4v acc[2][4];
#pragma unroll
    for (int s = 0; s < 2; ++s)
#pragma unroll
        for (int c = 0; c < 4; ++c) acc[s][c] = (f4v){0.f, 0.f, 0.f, 0.f};

    stage(0, 0);
    __syncthreads();
    for (int t = 0; t < 6; ++t) {
        const int kt = t * 64;
        const int buf = t & 1;
        if (t < 5) stage(kt + 64, buf ^ 1);
        s8v ah[2][2];
#pragma unroll
        for (int s = 0; s < 2; ++s)
#pragma unroll
            for (int kf = 0; kf < 2; ++kf)
                ah[s][kf] = *(const s8v*)&xh[(size_t)(gw + s * 16 + l15) * 384 + kt + kf * 32 + q * 8];
#pragma unroll
        for (int kf = 0; kf < 2; ++kf)
#pragma unroll
            for (int cs = 0; cs < 4; ++cs) {
                s8v bh = *(const s8v*)&sm.stg.B[buf][kf * 4 + cs][l * 8];
                s8v bl = *(const s8v*)&sm.stg.B[buf][8 + kf * 4 + cs][l * 8];
#pragma unroll
                for (int s = 0; s < 2; ++s) {
                    acc[s][cs] = __builtin_amdgcn_mfma_f32_16x16x32_f16(*(h8v*)&ah[s][kf], *(h8v*)&bh, acc[s][cs], 0, 0, 0);
                    acc[s][cs] = __builtin_amdgcn_mfma_f32_16x16x32_f16(*(h8v*)&ah[s][kf], *(h8v*)&bl, acc[s][cs], 0, 0, 0);
                }
            }
        __syncthreads();
    }

#pragma unroll
    for (int s = 0; s < 2; ++s)
#pragma unroll
        for (int cs = 0; cs < 4; ++cs) {
            int c = cs * 16 + l15;
            float bv = b1[c0 + c];
#pragma unroll
            for (int r = 0; r < 4; ++r) {
                int px = wave * 32 + s * 16 + q * 4 + r;
                sm.bounce[px * 66 + c] = f2h(fmaxf(acc[s][cs][r] + bv, 0.f));
            }
        }
    __syncthreads();
    {
        int px = tid >> 1, half = tid & 1;
        u32 tmp[16];
#pragma unroll
        for (int j = 0; j < 16; ++j)
            tmp[j] = *(const u32*)&sm.bounce[px * 66 + half * 32 + j * 2];
        size_t o = (size_t)(g0 + px) * 256 + c0 + half * 32;
#pragma unroll
        for (int j = 0; j < 4; ++j)
            *(s8v*)&hh[o + j * 8] = ((s8v*)tmp)[j];
    }
}

// ---------------------------------------------------------------------------
// K2: FUSED conv2 + L2-normalize. 64 px x 128 couts, W2 hi staged (64 KB),
// 1-term f16 MFMA. Epilogue writes rf (fp32) + qi8 (int8, scale QSCALE).
// ---------------------------------------------------------------------------
__global__ __launch_bounds__(256) void k_gemm2n(const u16* __restrict__ hh,
                                                const u16* __restrict__ w2h,
                                                const float* __restrict__ b2,
                                                float* __restrict__ rf,
                                                signed char* __restrict__ qi8)
{
    __shared__ u16 Bs[64][512];   // 64 KB: cid = kf*8 + cst
    const int tid = threadIdx.x;
    const int wave = tid >> 6, l = tid & 63, l15 = l & 15, q = l >> 4;
    const int bx = blockIdx.x;
    const int xcd = bx & 7, k = bx >> 3;
    const int g0 = (xcd * 36 + k) * 64;

#pragma unroll
    for (int r = 0; r < 16; ++r) {
        int cid = r * 4 + wave;
        int kf = cid >> 3, cst = cid & 7;
        const u16* src = w2h + (size_t)(cst * 16 + l15) * 256 + kf * 32 + q * 8;
        __builtin_amdgcn_global_load_lds(
            (const __attribute__((address_space(1))) void*)src,
            (__attribute__((address_space(3))) void*)&Bs[cid][0],
            16, 0, 0);
    }
    __syncthreads();

    const int gw = g0 + wave * 16;
    f4v acc[8];
#pragma unroll
    for (int c = 0; c < 8; ++c) acc[c] = (f4v){0.f, 0.f, 0.f, 0.f};

#pragma unroll
    for (int kf = 0; kf < 8; ++kf) {
        s8v ah = *(const s8v*)&hh[(size_t)(gw + l15) * 256 + kf * 32 + q * 8];
#pragma unroll
        for (int cst = 0; cst < 8; ++cst) {
            s8v bh = *(const s8v*)&Bs[kf * 8 + cst][l * 8];
            acc[cst] = __builtin_amdgcn_mfma_f32_16x16x32_f16(*(h8v*)&ah, *(h8v*)&bh, acc[cst], 0, 0, 0);
        }
    }

    float ssq[4] = {0.f, 0.f, 0.f, 0.f};
#pragma unroll
    for (int cst = 0; cst < 8; ++cst) {
        float bv = b2[cst * 16 + l15];
#pragma unroll
        for (int r = 0; r < 4; ++r) {
            acc[cst][r] += bv;
            ssq[r] += acc[cst][r] * acc[cst][r];
        }
    }
#pragma unroll
    for (int r = 0; r < 4; ++r) {
        ssq[r] += __shfl_xor(ssq[r], 1, 64);
        ssq[r] += __shfl_xor(ssq[r], 2, 64);
        ssq[r] += __shfl_xor(ssq[r], 4, 64);
        ssq[r] += __shfl_xor(ssq[r], 8, 64);
        ssq[r] = 1.0f / fmaxf(sqrtf(ssq[r]), 1e-12f);
    }
#pragma unroll
    for (int cst = 0; cst < 8; ++cst)
#pragma unroll
        for (int r = 0; r < 4; ++r) {
            float val = acc[cst][r] * ssq[r];
            size_t o = (size_t)(gw + q * 4 + r) * 128 + cst * 16 + l15;
            rf[o] = val;
            int qv = __float2int_rn(fminf(fmaxf(val * QSCALE, -127.f), 127.f));
            qi8[o] = (signed char)qv;
        }
}

// ---------------------------------------------------------------------------
// K3: sim selection via i8 MFMA (16x16x64, K-frags of 64) + int sortable keys.
// s=4 (64 rows/wave, 256/block). acc init = 2^21 -> sims positive; key =
// (acc<<6)|((ct<<2)|cs) -> single lshl_add + umax per element. B tile 8 KB/iter
// (half of bf16). Regs ~154 combined -> (256,2) proven envelope.
// ---------------------------------------------------------------------------
__global__ __launch_bounds__(256, 2) void k_simtop(const signed char* __restrict__ qi,
                                                   int* __restrict__ cidx)
{
    __shared__ signed char Bs[2][8][1024];   // 16 KB double buffer
    const int tid  = threadIdx.x;
    const int wave = tid >> 6, l = tid & 63, l15 = l & 15, q = l >> 4;
    const int b     = blockIdx.z;
    const int rbase = blockIdx.x * 256;
    const int chunk = blockIdx.y;
    const int cbase = chunk * 576;
    const size_t base = (size_t)b * NHW;
    const int wr0 = rbase + wave * 64;

    // A fragments: 4 row-subtiles x 2 k-frags (K=64 each) -> 32 VGPRs
    i4v ah[4][2];
#pragma unroll
    for (int s = 0; s < 4; ++s) {
        int row = wr0 + s * 16 + l15;
#pragma unroll
        for (int kf = 0; kf < 2; ++kf)
            ah[s][kf] = *(const i4v*)&qi[(base + row) * 128 + kf * 64 + q * 16];
    }

    auto stage = [&](int colt, int buf) {
#pragma unroll
        for (int r = 0; r < 2; ++r) {
            int cid = r * 4 + wave;                 // cid = kf*4 + cs
            int kf = cid >> 2, cs = cid & 3;
            int col = colt + cs * 16 + l15;
            const signed char* src = qi + (base + col) * 128 + kf * 64 + q * 16;
            __builtin_amdgcn_global_load_lds(
                (const __attribute__((address_space(1))) void*)src,
                (__attribute__((address_space(3))) void*)&Bs[buf][cid][0],
                16, 0, 0);
        }
    };

    u32 bk[4][4];
#pragma unroll
    for (int s = 0; s < 4; ++s)
#pragma unroll
        for (int r = 0; r < 4; ++r) bk[s][r] = 0u;

    stage(cbase, 0);
    __syncthreads();

    for (int ct = 0; ct < 9; ++ct) {
        const int colt = cbase + ct * 64;
        const int buf  = ct & 1;
        if (ct < 8) stage(colt + 64, buf ^ 1);

        i4v acc[4][4];
#pragma unroll
        for (int s = 0; s < 4; ++s)
#pragma unroll
            for (int c = 0; c < 4; ++c) acc[s][c] = (i4v){IBIAS, IBIAS, IBIAS, IBIAS};

#pragma unroll
        for (int kf = 0; kf < 2; ++kf)
#pragma unroll
            for (int cs = 0; cs < 4; ++cs) {
                i4v bh = *(const i4v*)&Bs[buf][kf * 4 + cs][l * 16];
#pragma unroll
                for (int s = 0; s < 4; ++s)
                    acc[s][cs] = __builtin_amdgcn_mfma_i32_16x16x64_i8(ah[s][kf], bh, acc[s][cs], 0, 0, 0);
            }

        const u32 tagv = (u32)(ct << 2);
        const bool hasdiag = (colt < wr0 + 64) && (wr0 < colt + 64);
        if (hasdiag) {
#pragma unroll
            for (int s = 0; s < 4; ++s)
#pragma unroll
                for (int r = 0; r < 4; ++r) {
                    const int rr = wr0 + s * 16 + q * 4 + r;
                    u32 km = 0u;
#pragma unroll
                    for (int cs = 0; cs < 4; ++cs) {
                        u32 kk = ((u32)acc[s][cs][r] << 6) | (tagv | (u32)cs);
                        if (colt + cs * 16 + l15 == rr) kk = 0u;
                        km = kk > km ? kk : km;
                    }
                    bk[s][r] = km > bk[s][r] ? km : bk[s][r];
                }
        } else {
#pragma unroll
            for (int s = 0; s < 4; ++s)
#pragma unroll
                for (int r = 0; r < 4; ++r) {
                    u32 km = 0u;
#pragma unroll
                    for (int cs = 0; cs < 4; ++cs) {
                        u32 kk = ((u32)acc[s][cs][r] << 6) | (tagv | (u32)cs);
                        km = kk > km ? kk : km;
                    }
                    bk[s][r] = km > bk[s][r] ? km : bk[s][r];
                }
        }
        __syncthreads();
    }

    // decode keys, merge (sim,col) across 16 lanes per row; write chunk winner
#pragma unroll
    for (int s = 0; s < 4; ++s)
#pragma unroll
        for (int r = 0; r < 4; ++r) {
            u32 key = bk[s][r];
            int sv = (int)(key >> 6);            // biased int sim
            int ctw = (int)((key >> 2) & 15u);
            int csw = (int)(key & 3u);
            int col = cbase + ctw * 64 + csw * 16 + l15;
#pragma unroll
            for (int d = 1; d < 16; d <<= 1) {
                int ov = __shfl_xor(sv, d, 64);
                int oi = __shfl_xor(col, d, 64);
                bool p = (ov > sv) || (ov == sv && oi < col);
                sv  = p ? ov : sv;
                col = p ? oi : col;
            }
            if (l15 == 0) {
                int row = wr0 + s * 16 + q * 4 + r;
                cidx[(base + row) * NCHUNK + chunk] = col;
            }
        }
}

// ---------------------------------------------------------------------------
// K4: exact fp32 re-rank of 16 candidates + distance + mask (R8-proven)
// ---------------------------------------------------------------------------
__global__ __launch_bounds__(256) void k_finish(const float* __restrict__ rf,
                                                const int* __restrict__ cidx,
                                                float* __restrict__ out)
{
    const int tid = threadIdx.x;
    const int g = blockIdx.x * 16 + (tid >> 4);
    const int l15 = tid & 15;
    const int b = g / NHW;
    const size_t rowbase = (size_t)b * NHW;

    const float* x = rf + (size_t)g * 128;
    f4v x0 = *(const f4v*)&x[l15 * 8];
    f4v x1 = *(const f4v*)&x[l15 * 8 + 4];

    float bestS = -2.f; int bestI = 0;
#pragma unroll
    for (int j = 0; j < NCHUNK; ++j) {
        int c = cidx[(size_t)g * NCHUNK + j];
        const float* y = rf + (rowbase + c) * 128;
        f4v y0 = *(const f4v*)&y[l15 * 8];
        f4v y1 = *(const f4v*)&y[l15 * 8 + 4];
        float s = x0[0]*y0[0] + x0[1]*y0[1] + x0[2]*y0[2] + x0[3]*y0[3]
                + x1[0]*y1[0] + x1[1]*y1[1] + x1[2]*y1[2] + x1[3]*y1[3];
#pragma unroll
        for (int d = 1; d < 16; d <<= 1) s += __shfl_xor(s, d, 64);
        bool p = (s > bestS) || (s == bestS && c < bestI);
        bestS = p ? s : bestS;
        bestI = p ? c : bestI;
    }

    const float* y = rf + (rowbase + bestI) * 128;
    f4v y0 = *(const f4v*)&y[l15 * 8];
    f4v y1 = *(const f4v*)&y[l15 * 8 + 4];
    float d0 = x0[0]-y0[0], d1 = x0[1]-y0[1], d2 = x0[2]-y0[2], d3 = x0[3]-y0[3];
    float e0 = x1[0]-y1[0], e1 = x1[1]-y1[1], e2 = x1[2]-y1[2], e3 = x1[3]-y1[3];
    float ss = d0*d0 + d1*d1 + d2*d2 + d3*d3 + e0*e0 + e1*e1 + e2*e2 + e3*e3;
#pragma unroll
    for (int d = 1; d < 16; d <<= 1) ss += __shfl_xor(ss, d, 64);
    if (l15 == 0) {
        float dist = sqrtf(ss);
        out[NB * NHW + g] = dist;
        out[g] = dist > 0.2f ? 1.0f : 0.0f;
    }
}

// ===========================================================================
extern "C" void kernel_launch(void* const* d_in, const int* in_sizes, int n_in,
                              void* d_out, int out_size, void* d_ws, size_t ws_size,
                              hipStream_t stream) {
    const float* features = (const float*)d_in[0];
    const float* W1 = (const float*)d_in[1];
    const float* b1 = (const float*)d_in[2];
    const float* W2 = (const float*)d_in[3];
    const float* b2 = (const float*)d_in[4];
    float* out = (float*)d_out;
    float* ws  = (float*)d_ws;

    // ws layout (float offsets), peak 6,012,928 f = 24.1 MB:
    //   [0,       3538944)  xh (18432x384 f16)  -> after gemm1:
    //       rf  [0, 2359296) fp32
    //       qi8 [2359296, 2949120) int8 (589824 floats of space)
    //   [3538944, 5898240)  hh (18432x256 f16)  -> after gemm2n: cidx
    //   [5898240, 6012928)  w1h/w1l/w2h
    u16*   xh   = (u16*)ws;
    u16*   hh   = (u16*)(ws + 3538944);
    u16*   w1h  = (u16*)(ws + 5898240);
    u16*   w1l  = (u16*)(ws + 5947392);
    u16*   w2h  = (u16*)(ws + 5996544);
    float* rf   = ws;
    signed char* qi8 = (signed char*)(ws + 2359296);
    int*   cidx = (int*)(ws + 3538944);

    // transpose + f16 split of X; weight splits (W2 hi-only)
    k_xsplit<<<dim3(144, 2, NB), 256, 0, stream>>>(features, xh);
    k_wsplit<<<512, 256, 0, stream>>>(W1, W2, w1h, w1l, w2h);
    // conv1 (2-term f16 MFMA, 128px x 64cout, XCD-swizzled)
    k_gemm1<<<576, 256, 0, stream>>>(xh, w1h, w1l, b1, hh);
    // fused conv2 + normalize + i8 quantize (1-term f16 MFMA, 64px x 128cout)
    k_gemm2n<<<288, 256, 0, stream>>>(hh, w2h, b2, rf, qi8);
    // i8 sim selection: per-chunk argmax candidates (s=4, 256 rows/block)
    k_simtop<<<dim3(36, NCHUNK, NB), 256, 0, stream>>>(qi8, cidx);
    // exact fp32 re-rank of 16 candidates + distance + mask
    k_finish<<<1152, 256, 0, stream>>>(rf, cidx, out);
}